// Round 1
// baseline (50.944 us; speedup 1.0000x reference)
//
#include <hip/hip_runtime.h>
#include <math.h>

// ---- DCT constants (fp32) ----
#define A0c 0.35355339059327373f
#define C1c 0.4903926402016152f
#define C2c 0.46193976625564337f
#define C3c 0.41573480615127262f
#define C5c 0.27778511650980114f
#define C6c 0.19134171618254492f
#define C7c 0.09754516100806417f

#define IMG_W 512
#define IMG_HW (512 * 512)

// Swizzled LDS word offset for (channel, block, row, col-group-of-4 base).
// rr = r ^ (blk&7) spreads rows of a block across banks; the c XOR with blk
// bit3 spreads the two float4 halves. All float4 accesses stay 16B aligned
// and elements remain in ascending original-column order.
__device__ __forceinline__ int lds_base(int ch, int blk, int r, int c0) {
    int rr = r ^ (blk & 7);
    int cc = c0 ^ (((blk >> 3) & 1) << 2);
    return ((ch * 64 + blk) << 6) + (rr << 3) + cc;
}

// In-place 8-point DCT-II (rows of D = 0.5*c(u)*cos((2x+1)u*pi/16))
__device__ __forceinline__ void fdct8(float v[8]) {
    float s0 = v[0] + v[7], s1 = v[1] + v[6], s2 = v[2] + v[5], s3 = v[3] + v[4];
    float d0 = v[0] - v[7], d1 = v[1] - v[6], d2 = v[2] - v[5], d3 = v[3] - v[4];
    float e0 = s0 + s3, e1 = s1 + s2, f0 = s0 - s3, f1 = s1 - s2;
    v[0] = A0c * (e0 + e1);
    v[4] = A0c * (e0 - e1);
    v[2] = C2c * f0 + C6c * f1;
    v[6] = C6c * f0 - C2c * f1;
    v[1] = C1c * d0 + C3c * d1 + C5c * d2 + C7c * d3;
    v[3] = C3c * d0 - C7c * d1 - C1c * d2 - C5c * d3;
    v[5] = C5c * d0 - C1c * d1 + C7c * d2 + C3c * d3;
    v[7] = C7c * d0 - C5c * d1 + C3c * d2 - C1c * d3;
}

// In-place 8-point inverse: x[n] = sum_u D[u][n] c[u]
__device__ __forceinline__ void idct8(float v[8]) {
    float g0 = v[0], g1 = v[1], g2 = v[2], g3 = v[3];
    float g4 = v[4], g5 = v[5], g6 = v[6], g7 = v[7];
    float ep = A0c * (g0 + g4), em = A0c * (g0 - g4);
    float t26a = C2c * g2 + C6c * g6;
    float t26b = C6c * g2 - C2c * g6;
    float e0 = ep + t26a;
    float e1 = em + t26b;
    float e2 = em - t26b;
    float e3 = ep - t26a;
    float o0 = C1c * g1 + C3c * g3 + C5c * g5 + C7c * g7;
    float o1 = C3c * g1 - C7c * g3 - C1c * g5 - C5c * g7;
    float o2 = C5c * g1 - C1c * g3 + C7c * g5 + C3c * g7;
    float o3 = C7c * g1 - C5c * g3 + C3c * g5 - C1c * g7;
    v[0] = e0 + o0; v[7] = e0 - o0;
    v[1] = e1 + o1; v[6] = e1 - o1;
    v[2] = e2 + o2; v[5] = e2 - o2;
    v[3] = e3 + o3; v[4] = e3 - o3;
}

// soft quantize-dequantize: d = x/q; sr = d + 0.5*tanh(15*(d - round(d))); return sr*q
__device__ __forceinline__ float softq(float x, float q, float rq) {
    float d = x * rq;
    float rn = rintf(d);           // nearest-even, matches jnp.round
    float t = d - rn;              // in [-0.5, 0.5]
    float z = 15.0f * t;           // 50*TEMP = 15
    float za = fabsf(z);
    float e = __expf(-2.0f * za);  // >= e^-15, no denormal trouble
    float th = (1.0f - e) * __builtin_amdgcn_rcpf(1.0f + e);
    th = copysignf(th, z);
    return (d + 0.5f * th) * q;
}

template <int CH>
__device__ __forceinline__ void quant_block(float X[8][8]) {
    static constexpr float QL[64] = {
        16,11,10,16,24,40,51,61,  12,12,14,19,26,58,60,55,
        14,13,16,24,40,57,69,56,  14,17,22,29,51,87,80,62,
        18,22,37,56,68,109,103,77, 24,35,55,64,81,104,113,92,
        49,64,78,87,103,121,120,101, 72,92,95,98,112,100,103,99};
    static constexpr float QC[64] = {
        17,18,24,47,99,99,99,99,  18,21,26,66,99,99,99,99,
        24,26,56,99,99,99,99,99,  47,66,99,99,99,99,99,99,
        99,99,99,99,99,99,99,99,  99,99,99,99,99,99,99,99,
        99,99,99,99,99,99,99,99,  99,99,99,99,99,99,99,99};
#pragma unroll
    for (int u = 0; u < 8; ++u) {
#pragma unroll
        for (int v = 0; v < 8; ++v) {
            float q = (CH == 0) ? QL[u * 8 + v] : QC[u * 8 + v];
            float rq = (CH == 0) ? (1.0f / QL[u * 8 + v]) : (1.0f / QC[u * 8 + v]);
            X[u][v] = softq(X[u][v], q, rq);
        }
    }
}

__global__ __launch_bounds__(256) void jpeg_kernel(const float* __restrict__ x,
                                                   float* __restrict__ out) {
    __shared__ float lds[3 * 64 * 64];  // 48 KB: [ch][blk][64] swizzled

    const int wg = blockIdx.x;
    const int b = wg >> 6;     // batch
    const int gh = wg & 63;    // 8-row strip index
    const int tid = threadIdx.x;

    const float* xb = x + (size_t)b * 3 * IMG_HW + (size_t)gh * 8 * IMG_W;
    float* ob = out + (size_t)b * 3 * IMG_HW + (size_t)gh * 8 * IMG_W;

    // ---------- load + forward color ----------
#pragma unroll
    for (int i = 0; i < 4; ++i) {
        int n4 = i * 256 + tid;          // 0..1023 float4-slots of 8x512 strip
        int r = n4 >> 7;                 // 0..7
        int col4 = (n4 & 127) << 2;      // 0..508
        const float4 rv = *(const float4*)(xb + 0 * IMG_HW + r * IMG_W + col4);
        const float4 gv = *(const float4*)(xb + 1 * IMG_HW + r * IMG_W + col4);
        const float4 bv = *(const float4*)(xb + 2 * IMG_HW + r * IMG_W + col4);
        float4 yv, cbv, crv;
        {
            const float* rp = &rv.x; const float* gp = &gv.x; const float* bp = &bv.x;
            float* yp = &yv.x; float* cbp = &cbv.x; float* crp = &crv.x;
#pragma unroll
            for (int k = 0; k < 4; ++k) {
                float R = rp[k], G = gp[k], B = bp[k];
                yp[k]  = 0.299f * R + 0.587f * G + 0.114f * B - 0.5f;
                cbp[k] = -0.168736f * R - 0.331264f * G + 0.5f * B;
                crp[k] = 0.5f * R - 0.418688f * G - 0.081312f * B;
            }
        }
        int blk = col4 >> 3;
        int c0 = col4 & 7;
        *(float4*)&lds[lds_base(0, blk, r, c0)] = yv;
        *(float4*)&lds[lds_base(1, blk, r, c0)] = cbv;
        *(float4*)&lds[lds_base(2, blk, r, c0)] = crv;
    }
    __syncthreads();

    // ---------- per-block transform (192 threads: ch = tid/64, blk = tid%64) ----------
    if (tid < 192) {
        const int ch = tid >> 6;
        const int blk = tid & 63;
        float X[8][8];
#pragma unroll
        for (int r = 0; r < 8; ++r) {
            float4 lo = *(const float4*)&lds[lds_base(ch, blk, r, 0)];
            float4 hi = *(const float4*)&lds[lds_base(ch, blk, r, 4)];
            X[r][0] = lo.x; X[r][1] = lo.y; X[r][2] = lo.z; X[r][3] = lo.w;
            X[r][4] = hi.x; X[r][5] = hi.y; X[r][6] = hi.z; X[r][7] = hi.w;
        }
        // forward: rows (over y), then columns (over x)
#pragma unroll
        for (int r = 0; r < 8; ++r) fdct8(X[r]);
#pragma unroll
        for (int v = 0; v < 8; ++v) {
            float t[8];
#pragma unroll
            for (int u = 0; u < 8; ++u) t[u] = X[u][v];
            fdct8(t);
#pragma unroll
            for (int u = 0; u < 8; ++u) X[u][v] = t[u];
        }
        // quantize + soft round + dequantize
        if (ch == 0) quant_block<0>(X); else quant_block<1>(X);
        // inverse: columns, then rows
#pragma unroll
        for (int v = 0; v < 8; ++v) {
            float t[8];
#pragma unroll
            for (int u = 0; u < 8; ++u) t[u] = X[u][v];
            idct8(t);
#pragma unroll
            for (int u = 0; u < 8; ++u) X[u][v] = t[u];
        }
#pragma unroll
        for (int r = 0; r < 8; ++r) idct8(X[r]);
        // write back
#pragma unroll
        for (int r = 0; r < 8; ++r) {
            float4 lo, hi;
            lo.x = X[r][0]; lo.y = X[r][1]; lo.z = X[r][2]; lo.w = X[r][3];
            hi.x = X[r][4]; hi.y = X[r][5]; hi.z = X[r][6]; hi.w = X[r][7];
            *(float4*)&lds[lds_base(ch, blk, r, 0)] = lo;
            *(float4*)&lds[lds_base(ch, blk, r, 4)] = hi;
        }
    }
    __syncthreads();

    // ---------- inverse color + store ----------
#pragma unroll
    for (int i = 0; i < 4; ++i) {
        int n4 = i * 256 + tid;
        int r = n4 >> 7;
        int col4 = (n4 & 127) << 2;
        int blk = col4 >> 3;
        int c0 = col4 & 7;
        float4 yv = *(const float4*)&lds[lds_base(0, blk, r, c0)];
        float4 cbv = *(const float4*)&lds[lds_base(1, blk, r, c0)];
        float4 crv = *(const float4*)&lds[lds_base(2, blk, r, c0)];
        float4 Rv, Gv, Bv;
        {
            const float* yp = &yv.x; const float* cbp = &cbv.x; const float* crp = &crv.x;
            float* Rp = &Rv.x; float* Gp = &Gv.x; float* Bp = &Bv.x;
#pragma unroll
            for (int k = 0; k < 4; ++k) {
                float Y = yp[k] + 0.5f, Cb = cbp[k], Cr = crp[k];
                float R = Y + 1.402f * Cr;
                float G = Y - 0.344136f * Cb - 0.714136f * Cr;
                float B = Y + 1.772f * Cb;
                Rp[k] = fminf(fmaxf(R, 0.0f), 1.0f);
                Gp[k] = fminf(fmaxf(G, 0.0f), 1.0f);
                Bp[k] = fminf(fmaxf(B, 0.0f), 1.0f);
            }
        }
        *(float4*)(ob + 0 * IMG_HW + r * IMG_W + col4) = Rv;
        *(float4*)(ob + 1 * IMG_HW + r * IMG_W + col4) = Gv;
        *(float4*)(ob + 2 * IMG_HW + r * IMG_W + col4) = Bv;
    }
}

extern "C" void kernel_launch(void* const* d_in, const int* in_sizes, int n_in,
                              void* d_out, int out_size, void* d_ws, size_t ws_size,
                              hipStream_t stream) {
    const float* x = (const float*)d_in[0];
    float* out = (float*)d_out;
    const int B = in_sizes[0] / (3 * IMG_HW);   // 32
    const int n_wg = B * 64;                    // one WG per (batch, 8-row strip)
    hipLaunchKernelGGL(jpeg_kernel, dim3(n_wg), dim3(256), 0, stream, x, out);
}